// Round 1
// baseline (2579.114 us; speedup 1.0000x reference)
//
#include <hip/hip_runtime.h>

#define BB 4
#define NN 4096
#define DD 256
#define KK 16

// ---------------------------------------------------------------------------
// KNN: one block per (b,i). Each thread owns 16 candidate j's in registers.
// 16 rounds of block-wide argmin over packed keys ((distbits+1)<<32 | j):
// monotonic for non-negative f32 dist, tie-break = lower index (matches
// jax.lax.top_k). Neighbor ORDER doesn't matter downstream (softmax+einsum
// over k is permutation-invariant) — only the set must match.
// ---------------------------------------------------------------------------
__global__ __launch_bounds__(256) void knn_kernel(const float* __restrict__ xyz,
                                                  int* __restrict__ knn) {
  const int row = blockIdx.x;
  const int b = row >> 12, i = row & (NN - 1);
  const int t = threadIdx.x;
  const float* xb = xyz + (size_t)b * NN * 3;
  const float xi = xb[i * 3 + 0], yi = xb[i * 3 + 1], zi = xb[i * 3 + 2];
  unsigned long long cand[16];
#pragma unroll
  for (int c = 0; c < 16; ++c) {
    int j = t + 256 * c;
    float dx = xi - xb[j * 3 + 0];
    float dy = yi - xb[j * 3 + 1];
    float dz = zi - xb[j * 3 + 2];
    float d = dx * dx + dy * dy + dz * dz;
    unsigned long long fb = (unsigned long long)(__float_as_uint(d)) + 1ull;
    cand[c] = (fb << 32) | (unsigned int)j;
  }
  __shared__ unsigned long long red[4];
  unsigned long long lastkey = 0ull;
  for (int r = 0; r < KK; ++r) {
    unsigned long long lmin = ~0ull;
#pragma unroll
    for (int c = 0; c < 16; ++c) {
      unsigned long long v = cand[c];
      if (v > lastkey && v < lmin) lmin = v;
    }
#pragma unroll
    for (int off = 32; off > 0; off >>= 1) {
      unsigned long long o = __shfl_down(lmin, off, 64);
      if (o < lmin) lmin = o;
    }
    if ((t & 63) == 0) red[t >> 6] = lmin;
    __syncthreads();
    if (t == 0) {
      unsigned long long m = red[0];
      if (red[1] < m) m = red[1];
      if (red[2] < m) m = red[2];
      if (red[3] < m) m = red[3];
      red[0] = m;
      knn[row * KK + r] = (int)(m & 0xFFFFFFFFull);
    }
    __syncthreads();
    lastkey = red[0];
    __syncthreads();  // protect red[] reuse next round
  }
}

// ---------------------------------------------------------------------------
// q/k/v projections: block = 32 rows, thread t = output channel t.
// Weight rows read from global (L2-resident, reused 32x per block).
// ---------------------------------------------------------------------------
__global__ __launch_bounds__(256) void proj_kernel(
    const float* __restrict__ feats, const float* __restrict__ wq,
    const float* __restrict__ wk, const float* __restrict__ wv,
    float* __restrict__ q, float* __restrict__ kf, float* __restrict__ vf) {
  __shared__ float fs[32 * DD];
  const int t = threadIdx.x;
  const size_t r0 = (size_t)blockIdx.x * 32;
  for (int idx = t; idx < 32 * DD; idx += 256) fs[idx] = feats[r0 * DD + idx];
  __syncthreads();
  const float* wmat[3] = {wq, wk, wv};
  float* omat[3] = {q, kf, vf};
  for (int m = 0; m < 3; ++m) {
    const float4* w4 = (const float4*)(wmat[m] + (size_t)t * DD);
    float acc[32];
#pragma unroll
    for (int r = 0; r < 32; ++r) acc[r] = 0.f;
    for (int dq = 0; dq < DD / 4; ++dq) {
      float4 w = w4[dq];
#pragma unroll
      for (int r = 0; r < 32; ++r) {
        const float4 f = *(const float4*)&fs[r * DD + dq * 4];
        acc[r] += f.x * w.x + f.y * w.y + f.z * w.z + f.w * w.w;
      }
    }
#pragma unroll
    for (int r = 0; r < 32; ++r) omat[m][(r0 + r) * DD + t] = acc[r];
  }
}

// ---------------------------------------------------------------------------
// Fused edge kernel: one block per point (b,i); thread t = channel t.
// pos_embed(33) -> pos_encode(256) -> edges -> MLP(256->256 relu 256->256)
// -> softmax over k -> weighted sum with (v+pe) -> +feats -> res (pre-BN).
// LDS: edges[16][256] (reused for h), vpe[16][256], emb[16][33]. ~35 KB.
// ---------------------------------------------------------------------------
__global__ __launch_bounds__(256) void edge_kernel(
    const float* __restrict__ xyz, const float* __restrict__ feats,
    const float* __restrict__ q, const float* __restrict__ kf,
    const float* __restrict__ vf, const int* __restrict__ knn,
    const float* __restrict__ g_w1, const float* __restrict__ g_b1,
    const float* __restrict__ g_w2, const float* __restrict__ g_b2,
    const float* __restrict__ pe_w, const float* __restrict__ pe_b,
    float* __restrict__ res) {
  const int row = blockIdx.x;
  const int b = row >> 12, i = row & (NN - 1);
  const int t = threadIdx.x;
  __shared__ float edges_s[KK][DD];
  __shared__ float vpe_s[KK][DD];
  __shared__ float emb_s[KK][33];
  __shared__ int js[KK];
  if (t < KK) js[t] = knn[row * KK + t];
  __syncthreads();
  if (t < 48) {  // (k, coord) pairs
    const int k = t / 3, c = t % 3;
    const float* xb = xyz + (size_t)b * NN * 3;
    const float pd = xb[i * 3 + c] - xb[js[k] * 3 + c];
    emb_s[k][c] = pd;
    const float fr[5] = {1.f, 8.75f, 16.5f, 24.25f, 32.f};  // linspace(1,32,5)
#pragma unroll
    for (int f = 0; f < 5; ++f) {
      emb_s[k][3 + f * 6 + c] = sinf(pd * fr[f]);
      emb_s[k][3 + f * 6 + 3 + c] = cosf(pd * fr[f]);
    }
  }
  __syncthreads();
  // pos_encode for all 16 neighbors, channel t
  float pwr[33];
  const float* pw = pe_w + t * 33;
#pragma unroll
  for (int c = 0; c < 33; ++c) pwr[c] = pw[c];
  const float peb = pe_b[t];
  float pe[KK];
#pragma unroll
  for (int k = 0; k < KK; ++k) {
    float acc = peb;
#pragma unroll
    for (int c = 0; c < 33; ++c) acc += pwr[c] * emb_s[k][c];
    pe[k] = acc;
  }
  const float qv = q[(size_t)row * DD + t];
#pragma unroll
  for (int k = 0; k < KK; ++k) {
    const size_t jr = ((size_t)(b * NN + js[k])) * DD + t;
    edges_s[k][t] = qv - kf[jr] + pe[k];
    vpe_s[k][t] = vf[jr] + pe[k];
  }
  __syncthreads();
  // layer 1: h[k] = relu(W1[t,:] . edges[k,:] + b1[t])
  float h[KK];
  {
    const float b1 = g_b1[t];
#pragma unroll
    for (int k = 0; k < KK; ++k) h[k] = b1;
    const float4* w1 = (const float4*)(g_w1 + (size_t)t * DD);
    for (int dq = 0; dq < DD / 4; ++dq) {
      float4 w = w1[dq];
#pragma unroll
      for (int k = 0; k < KK; ++k) {
        float4 e = *(const float4*)&edges_s[k][dq * 4];
        h[k] += e.x * w.x + e.y * w.y + e.z * w.z + e.w * w.w;
      }
    }
  }
  __syncthreads();
#pragma unroll
  for (int k = 0; k < KK; ++k) edges_s[k][t] = fmaxf(h[k], 0.f);
  __syncthreads();
  // layer 2: a[k] = W2[t,:] . h[k,:] + b2[t]
  float a[KK];
  {
    const float b2 = g_b2[t];
#pragma unroll
    for (int k = 0; k < KK; ++k) a[k] = b2;
    const float4* w2 = (const float4*)(g_w2 + (size_t)t * DD);
    for (int dq = 0; dq < DD / 4; ++dq) {
      float4 w = w2[dq];
#pragma unroll
      for (int k = 0; k < KK; ++k) {
        float4 e = *(const float4*)&edges_s[k][dq * 4];
        a[k] += e.x * w.x + e.y * w.y + e.z * w.z + e.w * w.w;
      }
    }
  }
  // softmax over k (per channel) + weighted sum of (v+pe) + residual
  float m = a[0];
#pragma unroll
  for (int k = 1; k < KK; ++k) m = fmaxf(m, a[k]);
  float s = 0.f;
#pragma unroll
  for (int k = 0; k < KK; ++k) {
    a[k] = __expf(a[k] - m);
    s += a[k];
  }
  float out = 0.f;
#pragma unroll
  for (int k = 0; k < KK; ++k) out += a[k] * vpe_s[k][t];
  out = out / s + feats[(size_t)row * DD + t];
  res[(size_t)row * DD + t] = out;
}

// ---------------------------------------------------------------------------
// BatchNorm stats: per-channel sum / sumsq over all B*N rows.
// ---------------------------------------------------------------------------
__global__ __launch_bounds__(256) void bn_stats(const float* __restrict__ res,
                                                float* __restrict__ sums,
                                                float* __restrict__ sumsq) {
  const int t = threadIdx.x;
  const size_t r0 = (size_t)blockIdx.x * 64;
  float s = 0.f, s2 = 0.f;
  for (int r = 0; r < 64; ++r) {
    float v = res[(r0 + r) * DD + t];
    s += v;
    s2 += v * v;
  }
  atomicAdd(&sums[t], s);
  atomicAdd(&sumsq[t], s2);
}

__global__ __launch_bounds__(256) void bn_apply(float* __restrict__ out,
                                                const float* __restrict__ sums,
                                                const float* __restrict__ sumsq,
                                                const float* __restrict__ bn_w,
                                                const float* __restrict__ bn_b) {
  const int idx = blockIdx.x * 256 + threadIdx.x;
  const int c = idx & (DD - 1);
  const float inv_n = 1.f / (float)(BB * NN);
  const float mean = sums[c] * inv_n;
  const float var = sumsq[c] * inv_n - mean * mean;
  const float v = out[idx];
  out[idx] = (v - mean) * rsqrtf(var + 1e-5f) * bn_w[c] + bn_b[c];
}

extern "C" void kernel_launch(void* const* d_in, const int* in_sizes, int n_in,
                              void* d_out, int out_size, void* d_ws,
                              size_t ws_size, hipStream_t stream) {
  (void)in_sizes; (void)n_in; (void)out_size; (void)ws_size;
  const float* xyz = (const float*)d_in[0];
  const float* feats = (const float*)d_in[1];
  const float* w_q = (const float*)d_in[2];
  const float* w_k = (const float*)d_in[3];
  const float* w_v = (const float*)d_in[4];
  const float* g_w1 = (const float*)d_in[5];
  const float* g_b1 = (const float*)d_in[6];
  const float* g_w2 = (const float*)d_in[7];
  const float* g_b2 = (const float*)d_in[8];
  const float* pe_w = (const float*)d_in[9];
  const float* pe_b = (const float*)d_in[10];
  const float* bn_w = (const float*)d_in[11];
  const float* bn_b = (const float*)d_in[12];
  float* out = (float*)d_out;

  const int BN = BB * NN;  // 16384
  // workspace layout (~51.5 MB): knn idx, q, kf, vf, bn accumulators
  int* knn = (int*)d_ws;
  float* q = (float*)d_ws + (size_t)BN * KK;
  float* kf = q + (size_t)BN * DD;
  float* vf = kf + (size_t)BN * DD;
  float* sums = vf + (size_t)BN * DD;
  float* sumsq = sums + DD;

  knn_kernel<<<BN, 256, 0, stream>>>(xyz, knn);
  proj_kernel<<<BN / 32, 256, 0, stream>>>(feats, w_q, w_k, w_v, q, kf, vf);
  edge_kernel<<<BN, 256, 0, stream>>>(xyz, feats, q, kf, vf, knn, g_w1, g_b1,
                                      g_w2, g_b2, pe_w, pe_b, out);
  hipMemsetAsync(sums, 0, 2 * DD * sizeof(float), stream);
  bn_stats<<<BN / 64, 256, 0, stream>>>(out, sums, sumsq);
  bn_apply<<<BN, 256, 0, stream>>>(out, sums, sumsq, bn_w, bn_b);
}

// Round 2
// 838.796 us; speedup vs baseline: 3.0748x; 3.0748x over previous
//
#include <hip/hip_runtime.h>

#define BB 4
#define NN 4096
#define DD 256
#define KK 16
#define PTS 2

typedef __bf16 bf16;
typedef __attribute__((ext_vector_type(8))) __bf16 bf16x8;
typedef __attribute__((ext_vector_type(4))) float f32x4;

// ---------------------------------------------------------------------------
// Prep: convert weights to bf16. pe_w padded [256][64] (cols 33..63 = 0).
// ---------------------------------------------------------------------------
__global__ __launch_bounds__(256) void prep_kernel(
    const float* __restrict__ w1, const float* __restrict__ w2,
    const float* __restrict__ pw, bf16* __restrict__ w1b,
    bf16* __restrict__ w2b, bf16* __restrict__ pwb) {
  const int idx = blockIdx.x * 256 + threadIdx.x;  // 65536
  w1b[idx] = (bf16)w1[idx];
  w2b[idx] = (bf16)w2[idx];
  if (idx < 256 * 64) {
    const int n = idx >> 6, c = idx & 63;
    pwb[idx] = (c < 33) ? (bf16)pw[n * 33 + c] : (bf16)0.f;
  }
}

// ---------------------------------------------------------------------------
// KNN (unchanged from R1, verified): packed (distbits+1)<<32|j argmin rounds.
// Neighbor order irrelevant downstream (softmax+einsum permutation-invariant).
// ---------------------------------------------------------------------------
__global__ __launch_bounds__(256) void knn_kernel(const float* __restrict__ xyz,
                                                  int* __restrict__ knn) {
  const int row = blockIdx.x;
  const int b = row >> 12, i = row & (NN - 1);
  const int t = threadIdx.x;
  const float* xb = xyz + (size_t)b * NN * 3;
  const float xi = xb[i * 3 + 0], yi = xb[i * 3 + 1], zi = xb[i * 3 + 2];
  unsigned long long cand[16];
#pragma unroll
  for (int c = 0; c < 16; ++c) {
    int j = t + 256 * c;
    float dx = xi - xb[j * 3 + 0];
    float dy = yi - xb[j * 3 + 1];
    float dz = zi - xb[j * 3 + 2];
    float d = dx * dx + dy * dy + dz * dz;
    unsigned long long fb = (unsigned long long)(__float_as_uint(d)) + 1ull;
    cand[c] = (fb << 32) | (unsigned int)j;
  }
  __shared__ unsigned long long red[4];
  unsigned long long lastkey = 0ull;
  for (int r = 0; r < KK; ++r) {
    unsigned long long lmin = ~0ull;
#pragma unroll
    for (int c = 0; c < 16; ++c) {
      unsigned long long v = cand[c];
      if (v > lastkey && v < lmin) lmin = v;
    }
#pragma unroll
    for (int off = 32; off > 0; off >>= 1) {
      unsigned long long o = __shfl_down(lmin, off, 64);
      if (o < lmin) lmin = o;
    }
    if ((t & 63) == 0) red[t >> 6] = lmin;
    __syncthreads();
    if (t == 0) {
      unsigned long long m = red[0];
      if (red[1] < m) m = red[1];
      if (red[2] < m) m = red[2];
      if (red[3] < m) m = red[3];
      red[0] = m;
      knn[row * KK + r] = (int)(m & 0xFFFFFFFFull);
    }
    __syncthreads();
    lastkey = red[0];
    __syncthreads();
  }
}

// ---------------------------------------------------------------------------
// q/k/v projections. q fp32; kf/vf written bf16 (consumed bf16 downstream).
// ---------------------------------------------------------------------------
__global__ __launch_bounds__(256) void proj_kernel(
    const float* __restrict__ feats, const float* __restrict__ wq,
    const float* __restrict__ wk, const float* __restrict__ wv,
    float* __restrict__ q, bf16* __restrict__ kfb, bf16* __restrict__ vfb) {
  __shared__ float fs[32 * DD];
  const int t = threadIdx.x;
  const size_t r0 = (size_t)blockIdx.x * 32;
  for (int idx = t; idx < 32 * DD; idx += 256) fs[idx] = feats[r0 * DD + idx];
  __syncthreads();
  const float* wmat[3] = {wq, wk, wv};
  for (int m = 0; m < 3; ++m) {
    const float4* w4 = (const float4*)(wmat[m] + (size_t)t * DD);
    float acc[32];
#pragma unroll
    for (int r = 0; r < 32; ++r) acc[r] = 0.f;
    for (int dq = 0; dq < DD / 4; ++dq) {
      float4 w = w4[dq];
#pragma unroll
      for (int r = 0; r < 32; ++r) {
        const float4 f = *(const float4*)&fs[r * DD + dq * 4];
        acc[r] += f.x * w.x + f.y * w.y + f.z * w.z + f.w * w.w;
      }
    }
    if (m == 0) {
#pragma unroll
      for (int r = 0; r < 32; ++r) q[(r0 + r) * DD + t] = acc[r];
    } else if (m == 1) {
#pragma unroll
      for (int r = 0; r < 32; ++r) kfb[(r0 + r) * DD + t] = (bf16)acc[r];
    } else {
#pragma unroll
      for (int r = 0; r < 32; ++r) vfb[(r0 + r) * DD + t] = (bf16)acc[r];
    }
  }
}

// ---------------------------------------------------------------------------
// Fused edge kernel v2 (MFMA). 1 block = 2 points, 4 waves.
// Wave w owns output cols [w*64, w*64+64). 16x16x32 bf16 MFMA:
//   A[m=lane&15][k=quad*8+j]  (m = neighbor index)
//   B[k=quad*8+j][n=lane&15]  (row-major weight rows -> contiguous 16B)
//   C/D: col=lane&15, row=quad*4+reg
// Phases: emb -> pe(MFMA) -> edges -> L1(MFMA,relu) -> L2(MFMA) ->
//         in-register softmax over 16 rows (shfl_xor 16/32) -> combine.
// ---------------------------------------------------------------------------
__global__ __launch_bounds__(256) void edge_v2(
    const float* __restrict__ xyz, const float* __restrict__ feats,
    const float* __restrict__ q, const bf16* __restrict__ kfb,
    const bf16* __restrict__ vfb, const int* __restrict__ knn,
    const bf16* __restrict__ w1b, const float* __restrict__ g_b1,
    const bf16* __restrict__ w2b, const float* __restrict__ g_b2,
    const bf16* __restrict__ pwb, const float* __restrict__ pe_b,
    float* __restrict__ res) {
  const int t = threadIdx.x;
  const int lane = t & 63;
  const int wv = t >> 6;      // wave 0..3
  const int m = lane & 15;    // tile col / A row
  const int qd = lane >> 4;   // quad 0..3
  const int row0 = blockIdx.x * PTS;
  const int b = row0 >> 12;   // PTS=2, NN even: block never straddles batch

  __shared__ __align__(16) bf16 emb_s[PTS][16][80];   // stride 160B (16B-al)
  __shared__ __align__(16) bf16 ab_s[PTS][16][264];   // edges, then h
  __shared__ __align__(16) bf16 pe_s[PTS][16][264];
  __shared__ int js_s[PTS][16];

  if (t < PTS * 16) js_s[t >> 4][t & 15] = knn[(row0 + (t >> 4)) * KK + (t & 15)];
  __syncthreads();

  // ---- phase A: positional embedding (bf16), zero-padded cols 33..79 ----
  const float* xb = xyz + (size_t)b * NN * 3;
  for (int p = 0; p < PTS; ++p) {
    const int i = (row0 + p) & (NN - 1);
    for (int e = t; e < 16 * 80; e += 256) {
      const int k = e / 80, c = e % 80;
      float val = 0.f;
      if (c < 33) {
        const int cc = (c < 3) ? c : (c - 3) % 3;
        const float pd = xb[i * 3 + cc] - xb[js_s[p][k] * 3 + cc];
        if (c < 3) {
          val = pd;
        } else {
          const int f = (c - 3) / 6;
          const float x = pd * fmaf(7.75f, (float)f, 1.0f);  // linspace(1,32,5)
          val = (((c - 3) % 6) < 3) ? __sinf(x) : __cosf(x);
        }
      }
      emb_s[p][k][c] = (bf16)val;
    }
  }
  __syncthreads();

  // ---- phase B: pos_encode = emb @ pe_w^T + pe_b via MFMA (K=64 padded) ----
  for (int tt = 0; tt < 4; ++tt) {
    const int c0 = wv * 64 + tt * 16;
    const bf16x8 b0 = *(const bf16x8*)(pwb + (size_t)(c0 + m) * 64 + qd * 8);
    const bf16x8 b1 = *(const bf16x8*)(pwb + (size_t)(c0 + m) * 64 + 32 + qd * 8);
    const float bias = pe_b[c0 + m];
#pragma unroll
    for (int p = 0; p < PTS; ++p) {
      bf16x8 a0 = *(const bf16x8*)(&emb_s[p][m][qd * 8]);
      bf16x8 a1 = *(const bf16x8*)(&emb_s[p][m][32 + qd * 8]);
      f32x4 c = {bias, bias, bias, bias};
      c = __builtin_amdgcn_mfma_f32_16x16x32_bf16(a0, b0, c, 0, 0, 0);
      c = __builtin_amdgcn_mfma_f32_16x16x32_bf16(a1, b1, c, 0, 0, 0);
#pragma unroll
      for (int r = 0; r < 4; ++r) pe_s[p][qd * 4 + r][c0 + m] = (bf16)c[r];
    }
  }
  __syncthreads();

  // ---- phase C: edges = q - k_g + pe  (thread = channel t) ----
  for (int p = 0; p < PTS; ++p) {
    const int row = row0 + p;
    const float qv = q[(size_t)row * DD + t];
#pragma unroll
    for (int k = 0; k < KK; ++k) {
      const int j = js_s[p][k];
      const float e =
          qv - (float)kfb[((size_t)(b * NN + j)) * DD + t] + (float)pe_s[p][k][t];
      ab_s[p][k][t] = (bf16)e;
    }
  }
  __syncthreads();

  // ---- phase D: h = relu(edges @ W1^T + b1) ----
  bf16x8 afrag[PTS][8];
#pragma unroll
  for (int p = 0; p < PTS; ++p)
#pragma unroll
    for (int f = 0; f < 8; ++f)
      afrag[p][f] = *(const bf16x8*)(&ab_s[p][m][f * 32 + qd * 8]);
  __syncthreads();  // all A cached before h overwrites ab_s
  for (int tt = 0; tt < 4; ++tt) {
    const int c0 = wv * 64 + tt * 16;
    bf16x8 bfr[8];
#pragma unroll
    for (int f = 0; f < 8; ++f)
      bfr[f] = *(const bf16x8*)(w1b + (size_t)(c0 + m) * DD + f * 32 + qd * 8);
    const float bias = g_b1[c0 + m];
#pragma unroll
    for (int p = 0; p < PTS; ++p) {
      f32x4 c = {bias, bias, bias, bias};
#pragma unroll
      for (int f = 0; f < 8; ++f)
        c = __builtin_amdgcn_mfma_f32_16x16x32_bf16(afrag[p][f], bfr[f], c, 0, 0, 0);
#pragma unroll
      for (int r = 0; r < 4; ++r)
        ab_s[p][qd * 4 + r][c0 + m] = (bf16)fmaxf(c[r], 0.f);
    }
  }
  __syncthreads();

  // ---- phase E: a = h @ W2^T + b2, fused softmax over k + combine ----
#pragma unroll
  for (int p = 0; p < PTS; ++p)
#pragma unroll
    for (int f = 0; f < 8; ++f)
      afrag[p][f] = *(const bf16x8*)(&ab_s[p][m][f * 32 + qd * 8]);
  for (int tt = 0; tt < 4; ++tt) {
    const int c0 = wv * 64 + tt * 16;
    bf16x8 bfr[8];
#pragma unroll
    for (int f = 0; f < 8; ++f)
      bfr[f] = *(const bf16x8*)(w2b + (size_t)(c0 + m) * DD + f * 32 + qd * 8);
    const float bias = g_b2[c0 + m];
#pragma unroll
    for (int p = 0; p < PTS; ++p) {
      f32x4 c = {bias, bias, bias, bias};
#pragma unroll
      for (int f = 0; f < 8; ++f)
        c = __builtin_amdgcn_mfma_f32_16x16x32_bf16(afrag[p][f], bfr[f], c, 0, 0, 0);
      // lane holds a[rows qd*4+r][col c0+m]; softmax over all 16 rows
      float mx = fmaxf(fmaxf(c[0], c[1]), fmaxf(c[2], c[3]));
      mx = fmaxf(mx, __shfl_xor(mx, 16));
      mx = fmaxf(mx, __shfl_xor(mx, 32));
      float e[4];
      float den = 0.f;
#pragma unroll
      for (int r = 0; r < 4; ++r) {
        e[r] = __expf(c[r] - mx);
        den += e[r];
      }
      den += __shfl_xor(den, 16);
      den += __shfl_xor(den, 32);
      float num = 0.f;
#pragma unroll
      for (int r = 0; r < 4; ++r) {
        const int krow = qd * 4 + r;
        const int j = js_s[p][krow];
        const float vpe = (float)vfb[((size_t)(b * NN + j)) * DD + c0 + m] +
                          (float)pe_s[p][krow][c0 + m];
        num += e[r] * vpe;
      }
      num += __shfl_xor(num, 16);
      num += __shfl_xor(num, 32);
      if (qd == 0) {
        const size_t o = (size_t)(row0 + p) * DD + c0 + m;
        res[o] = num / den + feats[o];
      }
    }
  }
}

// ---------------------------------------------------------------------------
// BatchNorm
// ---------------------------------------------------------------------------
__global__ __launch_bounds__(256) void bn_stats(const float* __restrict__ res,
                                                float* __restrict__ sums,
                                                float* __restrict__ sumsq) {
  const int t = threadIdx.x;
  const size_t r0 = (size_t)blockIdx.x * 64;
  float s = 0.f, s2 = 0.f;
  for (int r = 0; r < 64; ++r) {
    float v = res[(r0 + r) * DD + t];
    s += v;
    s2 += v * v;
  }
  atomicAdd(&sums[t], s);
  atomicAdd(&sumsq[t], s2);
}

__global__ __launch_bounds__(256) void bn_apply(float* __restrict__ out,
                                                const float* __restrict__ sums,
                                                const float* __restrict__ sumsq,
                                                const float* __restrict__ bn_w,
                                                const float* __restrict__ bn_b) {
  const int idx = blockIdx.x * 256 + threadIdx.x;
  const int c = idx & (DD - 1);
  const float inv_n = 1.f / (float)(BB * NN);
  const float mean = sums[c] * inv_n;
  const float var = sumsq[c] * inv_n - mean * mean;
  const float v = out[idx];
  out[idx] = (v - mean) * rsqrtf(var + 1e-5f) * bn_w[c] + bn_b[c];
}

extern "C" void kernel_launch(void* const* d_in, const int* in_sizes, int n_in,
                              void* d_out, int out_size, void* d_ws,
                              size_t ws_size, hipStream_t stream) {
  (void)in_sizes; (void)n_in; (void)out_size; (void)ws_size;
  const float* xyz = (const float*)d_in[0];
  const float* feats = (const float*)d_in[1];
  const float* w_q = (const float*)d_in[2];
  const float* w_k = (const float*)d_in[3];
  const float* w_v = (const float*)d_in[4];
  const float* g_w1 = (const float*)d_in[5];
  const float* g_b1 = (const float*)d_in[6];
  const float* g_w2 = (const float*)d_in[7];
  const float* g_b2 = (const float*)d_in[8];
  const float* pe_w = (const float*)d_in[9];
  const float* pe_b = (const float*)d_in[10];
  const float* bn_w = (const float*)d_in[11];
  const float* bn_b = (const float*)d_in[12];
  float* out = (float*)d_out;

  const int BN = BB * NN;  // 16384
  // ws layout (~35 MB), all 16B-aligned offsets
  char* w = (char*)d_ws;
  int* knn = (int*)w;                    w += (size_t)BN * KK * 4;      // 1 MB
  float* q = (float*)w;                  w += (size_t)BN * DD * 4;      // 16.8 MB
  bf16* kfb = (bf16*)w;                  w += (size_t)BN * DD * 2;      // 8.4 MB
  bf16* vfb = (bf16*)w;                  w += (size_t)BN * DD * 2;      // 8.4 MB
  float* sums = (float*)w;               w += DD * 4;
  float* sumsq = (float*)w;              w += DD * 4;
  bf16* w1b = (bf16*)w;                  w += (size_t)DD * DD * 2;
  bf16* w2b = (bf16*)w;                  w += (size_t)DD * DD * 2;
  bf16* pwb = (bf16*)w;                  w += (size_t)DD * 64 * 2;

  prep_kernel<<<DD * DD / 256, 256, 0, stream>>>(g_w1, g_w2, pe_w, w1b, w2b, pwb);
  knn_kernel<<<BN, 256, 0, stream>>>(xyz, knn);
  proj_kernel<<<BN / 32, 256, 0, stream>>>(feats, w_q, w_k, w_v, q, kfb, vfb);
  edge_v2<<<BN / PTS, 256, 0, stream>>>(xyz, feats, q, kfb, vfb, knn, w1b, g_b1,
                                        w2b, g_b2, pwb, pe_b, out);
  hipMemsetAsync(sums, 0, 2 * DD * sizeof(float), stream);
  bn_stats<<<BN / 64, 256, 0, stream>>>(out, sums, sumsq);
  bn_apply<<<BN, 256, 0, stream>>>(out, sums, sumsq, bn_w, bn_b);
}

// Round 3
// 679.485 us; speedup vs baseline: 3.7957x; 1.2345x over previous
//
#include <hip/hip_runtime.h>

#define BB 4
#define NN 4096
#define DD 256
#define KK 16
#define PTS 2

typedef __bf16 bf16;
typedef __attribute__((ext_vector_type(8))) __bf16 bf16x8;
typedef __attribute__((ext_vector_type(4))) __bf16 bf16x4;
typedef __attribute__((ext_vector_type(4))) float f32x4;

// ---------------------------------------------------------------------------
// Prep: convert all 5 weight matrices to bf16; pe_w padded [256][64].
// ---------------------------------------------------------------------------
__global__ __launch_bounds__(256) void prep_kernel(
    const float* __restrict__ wq, const float* __restrict__ wk,
    const float* __restrict__ wv, const float* __restrict__ w1,
    const float* __restrict__ w2, const float* __restrict__ pw,
    bf16* __restrict__ wqb, bf16* __restrict__ wkb, bf16* __restrict__ wvb,
    bf16* __restrict__ w1b, bf16* __restrict__ w2b, bf16* __restrict__ pwb) {
  const int idx = blockIdx.x * 256 + threadIdx.x;  // 65536
  wqb[idx] = (bf16)wq[idx];
  wkb[idx] = (bf16)wk[idx];
  wvb[idx] = (bf16)wv[idx];
  w1b[idx] = (bf16)w1[idx];
  w2b[idx] = (bf16)w2[idx];
  if (idx < 256 * 64) {
    const int n = idx >> 6, c = idx & 63;
    pwb[idx] = (c < 33) ? (bf16)pw[n * 33 + c] : (bf16)0.f;
  }
}

// ---------------------------------------------------------------------------
// KNN v2: one WAVE per point, no barriers. Lane holds 64 packed candidates
// ((distbits+1)<<32 | j) in regs; 16 rounds of filtered scan + shfl_xor
// butterfly min. Tie-break identical to R1 (verified).
// ---------------------------------------------------------------------------
__global__ __launch_bounds__(256, 2) void knn_v2(const float* __restrict__ xyz,
                                                 int* __restrict__ knn) {
  const int lane = threadIdx.x & 63;
  const int wv = threadIdx.x >> 6;
  const int row = blockIdx.x * 4 + wv;
  const int b = row >> 12, i = row & (NN - 1);
  const float* xb = xyz + (size_t)b * NN * 3;
  const float xi = xb[i * 3 + 0], yi = xb[i * 3 + 1], zi = xb[i * 3 + 2];
  unsigned long long cand[64];
#pragma unroll
  for (int c = 0; c < 64; ++c) {
    const int j = c * 64 + lane;
    const float dx = xi - xb[j * 3 + 0];
    const float dy = yi - xb[j * 3 + 1];
    const float dz = zi - xb[j * 3 + 2];
    const float d = dx * dx + dy * dy + dz * dz;
    const unsigned long long fb = (unsigned long long)(__float_as_uint(d)) + 1ull;
    cand[c] = (fb << 32) | (unsigned int)j;
  }
  unsigned long long lastkey = 0ull;
  unsigned int myj = 0u;
  for (int r = 0; r < KK; ++r) {
    unsigned long long lmin = ~0ull;
#pragma unroll
    for (int c = 0; c < 64; ++c) {
      const unsigned long long v = cand[c];
      if (v > lastkey && v < lmin) lmin = v;
    }
#pragma unroll
    for (int off = 1; off < 64; off <<= 1) {
      const unsigned long long o = __shfl_xor(lmin, off);
      if (o < lmin) lmin = o;
    }
    if (lane == r) myj = (unsigned int)lmin;
    lastkey = lmin;
  }
  if (lane < KK) knn[row * KK + lane] = (int)myj;
}

// ---------------------------------------------------------------------------
// proj MFMA: block = 64 rows, 4 waves; wave owns 16 rows x all 256 cols.
// A = feats rows (bf16 staged in LDS), B = weight rows (bf16, row-major).
// q stored fp32; k/v stored bf16.
// ---------------------------------------------------------------------------
__global__ __launch_bounds__(256, 4) void proj_mfma(
    const float* __restrict__ feats, const bf16* __restrict__ wqb,
    const bf16* __restrict__ wkb, const bf16* __restrict__ wvb,
    float* __restrict__ q, bf16* __restrict__ kfb, bf16* __restrict__ vfb) {
  const int t = threadIdx.x;
  const int lane = t & 63, wv = t >> 6;
  const int m = lane & 15, qd = lane >> 4;
  const size_t r0 = (size_t)blockIdx.x * 64;
  __shared__ __align__(16) bf16 fs[64][264];
  const float4* f4 = (const float4*)(feats + r0 * DD);
  for (int i = 0; i < 16; ++i) {
    const int e = i * 256 + t;  // 4096 float4 slots
    const float4 v = f4[e];
    bf16x4 w;
    w[0] = (bf16)v.x; w[1] = (bf16)v.y; w[2] = (bf16)v.z; w[3] = (bf16)v.w;
    *(bf16x4*)&fs[e >> 6][(e & 63) * 4] = w;
  }
  __syncthreads();
  bf16x8 afrag[8];
#pragma unroll
  for (int f = 0; f < 8; ++f)
    afrag[f] = *(const bf16x8*)&fs[wv * 16 + m][f * 32 + qd * 8];
  const bf16* wmat[3] = {wqb, wkb, wvb};
  for (int mat = 0; mat < 3; ++mat) {
    const bf16* wb = wmat[mat];
    for (int nt = 0; nt < 16; ++nt) {
      const int n = nt * 16 + m;
      bf16x8 bfr[8];
#pragma unroll
      for (int f = 0; f < 8; ++f)
        bfr[f] = *(const bf16x8*)(wb + (size_t)n * DD + f * 32 + qd * 8);
      f32x4 c = {0.f, 0.f, 0.f, 0.f};
#pragma unroll
      for (int f = 0; f < 8; ++f)
        c = __builtin_amdgcn_mfma_f32_16x16x32_bf16(afrag[f], bfr[f], c, 0, 0, 0);
#pragma unroll
      for (int rr = 0; rr < 4; ++rr) {
        const size_t o = (r0 + wv * 16 + qd * 4 + rr) * DD + n;
        if (mat == 0) q[o] = c[rr];
        else if (mat == 1) kfb[o] = (bf16)c[rr];
        else vfb[o] = (bf16)c[rr];
      }
    }
  }
}

// ---------------------------------------------------------------------------
// edge_v3: 2 points/block, 4 waves; wave owns 64 output cols.
// Fused: pe-MFMA epilogue builds edges (bufA) + vpe (regs) directly.
// Ping-pong bufA(edges) -> bufB(h) removes WAR hazards. 4 barriers total.
//   MFMA 16x16x32 bf16: A[m][qd*8+j], B[k=qd*8+j][n=m], C: col=m,row=qd*4+r
// ---------------------------------------------------------------------------
__global__ __launch_bounds__(256, 3) void edge_v3(
    const float* __restrict__ xyz, const float* __restrict__ feats,
    const float* __restrict__ q, const bf16* __restrict__ kfb,
    const bf16* __restrict__ vfb, const int* __restrict__ knn,
    const bf16* __restrict__ w1b, const float* __restrict__ g_b1,
    const bf16* __restrict__ w2b, const float* __restrict__ g_b2,
    const bf16* __restrict__ pwb, const float* __restrict__ pe_b,
    float* __restrict__ res) {
  const int t = threadIdx.x;
  const int lane = t & 63;
  const int wv = t >> 6;
  const int m = lane & 15;
  const int qd = lane >> 4;
  const int row0 = blockIdx.x * PTS;
  const int b = row0 >> 12;

  __shared__ __align__(16) bf16 emb_s[PTS][16][88];  // cols 33..63 zero
  __shared__ __align__(16) bf16 bufA[PTS][16][264];  // edges
  __shared__ __align__(16) bf16 bufB[PTS][16][264];  // h
  __shared__ int js_s[PTS][16];

  if (t < PTS * 16) js_s[t >> 4][t & 15] = knn[(row0 + (t >> 4)) * KK + (t & 15)];
  __syncthreads();

  // ---- emb fill ----
  const float* xb = xyz + (size_t)b * NN * 3;
  for (int p = 0; p < PTS; ++p) {
    const int i = (row0 + p) & (NN - 1);
    for (int e = t; e < 16 * 88; e += 256) {
      const int k = e / 88, c = e % 88;
      float val = 0.f;
      if (c < 33) {
        const int cc = (c < 3) ? c : (c - 3) % 3;
        const float pd = xb[i * 3 + cc] - xb[js_s[p][k] * 3 + cc];
        if (c < 3) {
          val = pd;
        } else {
          const int f = (c - 3) / 6;
          const float x = pd * fmaf(7.75f, (float)f, 1.0f);  // linspace(1,32,5)
          val = (((c - 3) % 6) < 3) ? __sinf(x) : __cosf(x);
        }
      }
      emb_s[p][k][c] = (bf16)val;
    }
  }
  __syncthreads();

  // ---- fused: pe (MFMA) -> edges (bufA) + vpe (regs) ----
  float vpe[4][PTS][4];
#pragma unroll
  for (int tt = 0; tt < 4; ++tt) {
    const int n = wv * 64 + tt * 16 + m;
    const bf16x8 b0 = *(const bf16x8*)(pwb + (size_t)n * 64 + qd * 8);
    const bf16x8 b1 = *(const bf16x8*)(pwb + (size_t)n * 64 + 32 + qd * 8);
    const float bias = pe_b[n];
#pragma unroll
    for (int p = 0; p < PTS; ++p) {
      const bf16x8 a0 = *(const bf16x8*)&emb_s[p][m][qd * 8];
      const bf16x8 a1 = *(const bf16x8*)&emb_s[p][m][32 + qd * 8];
      f32x4 c = {bias, bias, bias, bias};
      c = __builtin_amdgcn_mfma_f32_16x16x32_bf16(a0, b0, c, 0, 0, 0);
      c = __builtin_amdgcn_mfma_f32_16x16x32_bf16(a1, b1, c, 0, 0, 0);
      const float qv = q[(size_t)(row0 + p) * DD + n];
#pragma unroll
      for (int rr = 0; rr < 4; ++rr) {
        const int krow = qd * 4 + rr;
        const size_t jr = ((size_t)(b * NN + js_s[p][krow])) * DD + n;
        bufA[p][krow][n] = (bf16)(qv - (float)kfb[jr] + c[rr]);
        vpe[tt][p][rr] = (float)vfb[jr] + c[rr];
      }
    }
  }
  __syncthreads();

  // ---- layer 1: h = relu(edges @ W1^T + b1), bufA -> bufB ----
  {
    bf16x8 afrag[PTS][8];
#pragma unroll
    for (int p = 0; p < PTS; ++p)
#pragma unroll
      for (int f = 0; f < 8; ++f)
        afrag[p][f] = *(const bf16x8*)&bufA[p][m][f * 32 + qd * 8];
    for (int tt = 0; tt < 4; ++tt) {
      const int n = wv * 64 + tt * 16 + m;
      bf16x8 bfr[8];
#pragma unroll
      for (int f = 0; f < 8; ++f)
        bfr[f] = *(const bf16x8*)(w1b + (size_t)n * DD + f * 32 + qd * 8);
      const float bias = g_b1[n];
#pragma unroll
      for (int p = 0; p < PTS; ++p) {
        f32x4 c = {bias, bias, bias, bias};
#pragma unroll
        for (int f = 0; f < 8; ++f)
          c = __builtin_amdgcn_mfma_f32_16x16x32_bf16(afrag[p][f], bfr[f], c, 0, 0, 0);
#pragma unroll
        for (int rr = 0; rr < 4; ++rr)
          bufB[p][qd * 4 + rr][n] = (bf16)fmaxf(c[rr], 0.f);
      }
    }
  }
  __syncthreads();

  // ---- layer 2 + softmax + combine ----
  {
    bf16x8 afrag[PTS][8];
#pragma unroll
    for (int p = 0; p < PTS; ++p)
#pragma unroll
      for (int f = 0; f < 8; ++f)
        afrag[p][f] = *(const bf16x8*)&bufB[p][m][f * 32 + qd * 8];
#pragma unroll
    for (int tt = 0; tt < 4; ++tt) {
      const int n = wv * 64 + tt * 16 + m;
      bf16x8 bfr[8];
#pragma unroll
      for (int f = 0; f < 8; ++f)
        bfr[f] = *(const bf16x8*)(w2b + (size_t)n * DD + f * 32 + qd * 8);
      const float bias = g_b2[n];
#pragma unroll
      for (int p = 0; p < PTS; ++p) {
        f32x4 c = {bias, bias, bias, bias};
#pragma unroll
        for (int f = 0; f < 8; ++f)
          c = __builtin_amdgcn_mfma_f32_16x16x32_bf16(afrag[p][f], bfr[f], c, 0, 0, 0);
        float mx = fmaxf(fmaxf(c[0], c[1]), fmaxf(c[2], c[3]));
        mx = fmaxf(mx, __shfl_xor(mx, 16));
        mx = fmaxf(mx, __shfl_xor(mx, 32));
        float e[4], den = 0.f;
#pragma unroll
        for (int rr = 0; rr < 4; ++rr) {
          e[rr] = __expf(c[rr] - mx);
          den += e[rr];
        }
        den += __shfl_xor(den, 16);
        den += __shfl_xor(den, 32);
        float num = 0.f;
#pragma unroll
        for (int rr = 0; rr < 4; ++rr) num += e[rr] * vpe[tt][p][rr];
        num += __shfl_xor(num, 16);
        num += __shfl_xor(num, 32);
        if (qd == 0) {
          const size_t o = (size_t)(row0 + p) * DD + n;
          res[o] = num / den + feats[o];
        }
      }
    }
  }
}

// ---------------------------------------------------------------------------
// BatchNorm
// ---------------------------------------------------------------------------
__global__ __launch_bounds__(256) void bn_stats(const float* __restrict__ res,
                                                float* __restrict__ sums,
                                                float* __restrict__ sumsq) {
  const int t = threadIdx.x;
  const size_t r0 = (size_t)blockIdx.x * 32;
  float s = 0.f, s2 = 0.f;
  for (int r = 0; r < 32; ++r) {
    const float v = res[(r0 + r) * DD + t];
    s += v;
    s2 += v * v;
  }
  atomicAdd(&sums[t], s);
  atomicAdd(&sumsq[t], s2);
}

__global__ __launch_bounds__(256) void bn_apply(float* __restrict__ out,
                                                const float* __restrict__ sums,
                                                const float* __restrict__ sumsq,
                                                const float* __restrict__ bn_w,
                                                const float* __restrict__ bn_b) {
  const int idx = blockIdx.x * 256 + threadIdx.x;
  const int c = idx & (DD - 1);
  const float inv_n = 1.f / (float)(BB * NN);
  const float mean = sums[c] * inv_n;
  const float var = sumsq[c] * inv_n - mean * mean;
  const float v = out[idx];
  out[idx] = (v - mean) * rsqrtf(var + 1e-5f) * bn_w[c] + bn_b[c];
}

extern "C" void kernel_launch(void* const* d_in, const int* in_sizes, int n_in,
                              void* d_out, int out_size, void* d_ws,
                              size_t ws_size, hipStream_t stream) {
  (void)in_sizes; (void)n_in; (void)out_size; (void)ws_size;
  const float* xyz = (const float*)d_in[0];
  const float* feats = (const float*)d_in[1];
  const float* w_q = (const float*)d_in[2];
  const float* w_k = (const float*)d_in[3];
  const float* w_v = (const float*)d_in[4];
  const float* g_w1 = (const float*)d_in[5];
  const float* g_b1 = (const float*)d_in[6];
  const float* g_w2 = (const float*)d_in[7];
  const float* g_b2 = (const float*)d_in[8];
  const float* pe_w = (const float*)d_in[9];
  const float* pe_b = (const float*)d_in[10];
  const float* bn_w = (const float*)d_in[11];
  const float* bn_b = (const float*)d_in[12];
  float* out = (float*)d_out;

  const int BN = BB * NN;  // 16384
  char* w = (char*)d_ws;
  int* knn = (int*)w;       w += (size_t)BN * KK * 4;
  float* q = (float*)w;     w += (size_t)BN * DD * 4;
  bf16* kfb = (bf16*)w;     w += (size_t)BN * DD * 2;
  bf16* vfb = (bf16*)w;     w += (size_t)BN * DD * 2;
  float* sums = (float*)w;  w += DD * 4;
  float* sumsq = (float*)w; w += DD * 4;
  bf16* wqb = (bf16*)w;     w += (size_t)DD * DD * 2;
  bf16* wkb = (bf16*)w;     w += (size_t)DD * DD * 2;
  bf16* wvb = (bf16*)w;     w += (size_t)DD * DD * 2;
  bf16* w1b = (bf16*)w;     w += (size_t)DD * DD * 2;
  bf16* w2b = (bf16*)w;     w += (size_t)DD * DD * 2;
  bf16* pwb = (bf16*)w;     w += (size_t)DD * 64 * 2;

  prep_kernel<<<DD * DD / 256, 256, 0, stream>>>(w_q, w_k, w_v, g_w1, g_w2,
                                                 pe_w, wqb, wkb, wvb, w1b, w2b,
                                                 pwb);
  knn_v2<<<BN / 4, 256, 0, stream>>>(xyz, knn);
  proj_mfma<<<BN / 64, 256, 0, stream>>>(feats, wqb, wkb, wvb, q, kfb, vfb);
  edge_v3<<<BN / PTS, 256, 0, stream>>>(xyz, feats, q, kfb, vfb, knn, w1b, g_b1,
                                        w2b, g_b2, pwb, pe_b, out);
  hipMemsetAsync(sums, 0, 2 * DD * sizeof(float), stream);
  bn_stats<<<BN / 32, 256, 0, stream>>>(out, sums, sumsq);
  bn_apply<<<BN, 256, 0, stream>>>(out, sums, sumsq, bn_w, bn_b);
}